// Round 1
// baseline (79.382 us; speedup 1.0000x reference)
//
#include <hip/hip_runtime.h>
#include <hip/hip_bf16.h>

// Problem constants: B=1, NN=256, C=128, H=4, D=32
// Factorization:
//   w = x @ W_w                          (256x512)
//   a,b,c,v = per-head slices of w       (each 256x32 per head)
//   P = exp(scale * a b^T), Q = exp(scale * a c^T), R = exp(scale * b c^T)
//   norm[k] = clip(sum_j R[j,k] * sum_i P[i,j] Q[i,k], 1e-6)
//   Qn[i,k] = Q[i,k]/norm[k]
//   S = Qn R^T ; T = P R
//   x1 = (P.*S) v ; x2 = (Qn.*T) v ; y = x1.*x2
//   out = y @ W_proj + b_proj

constexpr int NN = 256;
constexpr int Cdim = 128;
constexpr int H = 4;
constexpr int Ddim = 32;

// float offsets in workspace
constexpr size_t OFF_W    = 0;                    // 256*512
constexpr size_t OFF_P    = OFF_W + 256*512;      // 4*256*256
constexpr size_t OFF_Q    = OFF_P + 4*65536;
constexpr size_t OFF_R    = OFF_Q + 4*65536;
constexpr size_t OFF_S    = OFF_R + 4*65536;
constexpr size_t OFF_T    = OFF_S + 4*65536;
constexpr size_t OFF_NORM = OFF_T + 4*65536;      // 4*256
constexpr size_t OFF_Y    = OFF_NORM + 1024;      // 256*128
// total = 1,475,584 floats ~= 5.9 MB

// ---------------- 1. w = x @ W_w  (256x128 @ 128x512) ----------------
__global__ void k_gemm_xw(const float* __restrict__ x, const float* __restrict__ Ww,
                          float* __restrict__ w) {
    __shared__ float xs[16][17];
    __shared__ float ws[16][17];
    int tx = threadIdx.x, ty = threadIdx.y;
    int col = blockIdx.x * 16 + tx;   // 0..511
    int row = blockIdx.y * 16 + ty;   // 0..255
    float acc = 0.f;
    for (int k0 = 0; k0 < 128; k0 += 16) {
        xs[ty][tx] = x[row * 128 + k0 + tx];
        ws[ty][tx] = Ww[(k0 + ty) * 512 + col];
        __syncthreads();
#pragma unroll
        for (int kk = 0; kk < 16; kk++) acc += xs[ty][kk] * ws[kk][tx];
        __syncthreads();
    }
    w[row * 512 + col] = acc;
}

// ---------------- 2. P, Q, R (exp of scaled dots) ----------------
// grid (16,16,H), block (16,16). Output tile r0..r0+15 x s0..s0+15.
__global__ void k_pqr(const float* __restrict__ w, float* __restrict__ P,
                      float* __restrict__ Q, float* __restrict__ R) {
    int h = blockIdx.z;
    int s0 = blockIdx.x * 16;
    int r0 = blockIdx.y * 16;
    int tx = threadIdx.x, ty = threadIdx.y;
    __shared__ float aR[16][33], bR[16][33], bS[16][33], cS[16][33];
    int tid = ty * 16 + tx;
    for (int idx = tid; idx < 16 * 32; idx += 256) {
        int rr = idx >> 5, dd = idx & 31;
        aR[rr][dd] = w[(size_t)(r0 + rr) * 512 +       h * 32 + dd];
        bR[rr][dd] = w[(size_t)(r0 + rr) * 512 + 128 + h * 32 + dd];
        bS[rr][dd] = w[(size_t)(s0 + rr) * 512 + 128 + h * 32 + dd];
        cS[rr][dd] = w[(size_t)(s0 + rr) * 512 + 256 + h * 32 + dd];
    }
    __syncthreads();
    float dab = 0.f, dac = 0.f, dbc = 0.f;
#pragma unroll
    for (int d = 0; d < 32; d++) {
        float av = aR[ty][d], brv = bR[ty][d];
        float bv = bS[tx][d], cv = cS[tx][d];
        dab += av * bv;
        dac += av * cv;
        dbc += brv * cv;
    }
    const float scale = 0.17677669529663687f;  // 1/sqrt(32)
    size_t base = (size_t)h * 65536 + (size_t)(r0 + ty) * 256 + (s0 + tx);
    P[base] = expf(scale * dab);
    Q[base] = expf(scale * dac);
    R[base] = expf(scale * dbc);
}

// ---------------- 3. norm[k] = clip(sum_j R[j,k] * sum_i P[i,j]Q[i,k]) ----------------
// grid (NN, H), block 256 (thread = j)
__global__ void k_norm(const float* __restrict__ P, const float* __restrict__ Q,
                       const float* __restrict__ R, float* __restrict__ norm) {
    int k = blockIdx.x, h = blockIdx.y;
    int j = threadIdx.x;
    const float* Ph = P + (size_t)h * 65536;
    const float* Qh = Q + (size_t)h * 65536;
    const float* Rh = R + (size_t)h * 65536;
    __shared__ float qcol[256];
    qcol[j] = Qh[(size_t)j * 256 + k];
    __syncthreads();
    float m = 0.f;
    for (int i = 0; i < 256; i++) m += Ph[(size_t)i * 256 + j] * qcol[i];
    float val = m * Rh[(size_t)j * 256 + k];
    __shared__ float red[256];
    red[j] = val;
    __syncthreads();
    for (int s = 128; s > 0; s >>= 1) {
        if (j < s) red[j] += red[j + s];
        __syncthreads();
    }
    if (j == 0) {
        float nv = red[0];
        norm[h * 256 + k] = nv < 1e-6f ? 1e-6f : nv;
    }
}

// ---------------- 4. Qn = Q / norm[k] (in place) ----------------
__global__ void k_qn(float* __restrict__ Q, const float* __restrict__ norm) {
    int idx = blockIdx.x * blockDim.x + threadIdx.x;  // 0..4*65536-1
    int h = idx >> 16, k = idx & 255;
    Q[idx] = Q[idx] / norm[h * 256 + k];
}

// ---------------- 5. 256x256x256 GEMM per head ----------------
// TRANSB=true : C[i,j] = sum_k A[i,k] B[j,k]   (NT)
// TRANSB=false: C[i,k] = sum_j A[i,j] B[j,k]   (NN)
template <bool TRANSB>
__global__ void k_gemm256(const float* __restrict__ A, const float* __restrict__ B,
                          float* __restrict__ Cout) {
    __shared__ float As[16][17];
    __shared__ float Bs[16][17];
    int h = blockIdx.z;
    const float* Ah = A + (size_t)h * 65536;
    const float* Bh = B + (size_t)h * 65536;
    float* Ch = Cout + (size_t)h * 65536;
    int tx = threadIdx.x, ty = threadIdx.y;
    int col = blockIdx.x * 16 + tx;
    int row = blockIdx.y * 16 + ty;
    float acc = 0.f;
    for (int k0 = 0; k0 < 256; k0 += 16) {
        As[ty][tx] = Ah[(size_t)row * 256 + k0 + tx];
        if (TRANSB)
            Bs[ty][tx] = Bh[(size_t)(blockIdx.x * 16 + ty) * 256 + k0 + tx];
        else
            Bs[ty][tx] = Bh[(size_t)(k0 + ty) * 256 + col];
        __syncthreads();
#pragma unroll
        for (int kk = 0; kk < 16; kk++) {
            if (TRANSB)
                acc += As[ty][kk] * Bs[tx][kk];
            else
                acc += As[ty][kk] * Bs[kk][tx];
        }
        __syncthreads();
    }
    Ch[(size_t)row * 256 + col] = acc;
}

// ---------------- 6. x1,x2 weighted-v and product ----------------
// grid (NN/8, H), block (32,8): thread.x = d, thread.y = local row
__global__ void k_x1x2(const float* __restrict__ P, const float* __restrict__ Qn,
                       const float* __restrict__ S, const float* __restrict__ T,
                       const float* __restrict__ w, float* __restrict__ y) {
    int h = blockIdx.y;
    int i0 = blockIdx.x * 8;
    int d = threadIdx.x;
    int rloc = threadIdx.y;
    __shared__ float wp[8][256];
    __shared__ float wq[8][256];
    const size_t hb = (size_t)h * 65536;
    int tid = rloc * 32 + d;
    for (int idx = tid; idx < 8 * 256; idx += 256) {
        int rr = idx >> 8, jj = idx & 255;
        size_t o = hb + (size_t)(i0 + rr) * 256 + jj;
        wp[rr][jj] = P[o] * S[o];
        wq[rr][jj] = Qn[o] * T[o];
    }
    __syncthreads();
    float x1 = 0.f, x2 = 0.f;
    for (int j = 0; j < 256; j++) {
        float vv = w[(size_t)j * 512 + 384 + h * 32 + d];
        x1 += wp[rloc][j] * vv;
        x2 += wq[rloc][j] * vv;
    }
    int i = i0 + rloc;
    y[(size_t)i * 128 + h * 32 + d] = x1 * x2;
}

// ---------------- 7. out = y @ W_proj + b_proj ----------------
__global__ void k_proj(const float* __restrict__ y, const float* __restrict__ Wp,
                       const float* __restrict__ bp, float* __restrict__ out) {
    __shared__ float ys[16][17];
    __shared__ float ws[16][17];
    int tx = threadIdx.x, ty = threadIdx.y;
    int col = blockIdx.x * 16 + tx;  // 0..127
    int row = blockIdx.y * 16 + ty;  // 0..255
    float acc = 0.f;
    for (int k0 = 0; k0 < 128; k0 += 16) {
        ys[ty][tx] = y[(size_t)row * 128 + k0 + tx];
        ws[ty][tx] = Wp[(size_t)(k0 + ty) * 128 + col];
        __syncthreads();
#pragma unroll
        for (int kk = 0; kk < 16; kk++) acc += ys[ty][kk] * ws[kk][tx];
        __syncthreads();
    }
    out[(size_t)row * 128 + col] = acc + bp[col];
}

extern "C" void kernel_launch(void* const* d_in, const int* in_sizes, int n_in,
                              void* d_out, int out_size, void* d_ws, size_t ws_size,
                              hipStream_t stream) {
    const float* x      = (const float*)d_in[0];
    const float* W_w    = (const float*)d_in[1];
    const float* W_proj = (const float*)d_in[2];
    const float* b_proj = (const float*)d_in[3];
    float* out = (float*)d_out;
    float* ws  = (float*)d_ws;

    float* w    = ws + OFF_W;
    float* P    = ws + OFF_P;
    float* Q    = ws + OFF_Q;
    float* R    = ws + OFF_R;
    float* S    = ws + OFF_S;
    float* T    = ws + OFF_T;
    float* norm = ws + OFF_NORM;
    float* y    = ws + OFF_Y;

    // 1. w = x @ W_w
    k_gemm_xw<<<dim3(32, 16), dim3(16, 16), 0, stream>>>(x, W_w, w);
    // 2. P, Q, R
    k_pqr<<<dim3(16, 16, H), dim3(16, 16), 0, stream>>>(w, P, Q, R);
    // 3. norm
    k_norm<<<dim3(NN, H), dim3(256), 0, stream>>>(P, Q, R, norm);
    // 4. Qn (in place on Q)
    k_qn<<<dim3(1024), dim3(256), 0, stream>>>(Q, norm);
    // 5. S = Qn R^T ; T = P R
    k_gemm256<true><<<dim3(16, 16, H), dim3(16, 16), 0, stream>>>(Q, R, S);
    k_gemm256<false><<<dim3(16, 16, H), dim3(16, 16), 0, stream>>>(P, R, T);
    // 6. x1, x2, y
    k_x1x2<<<dim3(32, H), dim3(32, 8), 0, stream>>>(P, Q, S, T, w, y);
    // 7. out
    k_proj<<<dim3(8, 16), dim3(16, 16), 0, stream>>>(y, W_proj, b_proj, out);
}

// Round 2
// 66.862 us; speedup vs baseline: 1.1872x; 1.1872x over previous
//
#include <hip/hip_runtime.h>
#include <hip/hip_bf16.h>

// B=1, NN=256, C=128, H=4, D=32
// Factorization:
//   w = x @ W_w (256x512); a,b,c,v = head slices at col offsets 0,128,256,384
//   P = exp(s a b^T), Q = exp(s a c^T), R = exp(s b c^T)   (s = 1/sqrt(32))
//   T = P R                      (per head 256^3 GEMM, NN)
//   norm[k] = clip(sum_i Q[i,k] T[i,k], 1e-6);  rn = 1/norm
//   S[i,j] = sum_k Q[i,k] (R[j,k] rn[k])        (NT GEMM, B scaled at load)
//   x1 = (P.*S) v ; x2[i,d] = sum_k Q[i,k] rn[k] T[i,k] v[k,d]
//   y = x1 .* x2 ; out = y @ W_proj + b_proj

constexpr int H = 4;

constexpr size_t OFF_W  = 0;                  // 256*512
constexpr size_t OFF_P  = OFF_W + 131072;     // 4*65536
constexpr size_t OFF_Q  = OFF_P + 262144;
constexpr size_t OFF_R  = OFF_Q + 262144;
constexpr size_t OFF_S  = OFF_R + 262144;
constexpr size_t OFF_T  = OFF_S + 262144;
constexpr size_t OFF_RN = OFF_T + 262144;     // 4*256
constexpr size_t OFF_Y  = OFF_RN + 1024;      // 256*128
// total 1,475,584 floats ~= 5.9 MB

// ---- generic 64x64-tile GEMM, 256 threads, 4x4 micro-tile -----------------
// NN: C[i,j] = sum_k A[i,k] B[k,j]     TRANSB(NT): C[i,j] = sum_k A[i,k] B[j,k]
// SCALEB (with TRANSB): B[j,k] *= rn[h*256+k]
template <int KTOT, bool TRANSB, bool SCALEB, bool BIAS>
__global__ __launch_bounds__(256) void k_gemm64(
    const float* __restrict__ A, const float* __restrict__ B,
    const float* __restrict__ rn, const float* __restrict__ bias,
    float* __restrict__ C, int ldA, int ldB, int ldC,
    size_t sA, size_t sB, size_t sC) {
    int h = blockIdx.z;
    const float* Ah = A + sA * h;
    const float* Bh = B + sB * h;
    float* Ch = C + sC * h;
    __shared__ float As[16][68];
    __shared__ float Bs[16][68];
    int i0 = blockIdx.y * 64, j0 = blockIdx.x * 64;
    int t = threadIdx.x;
    int lk = t & 15, lr = t >> 4;
    int tx = t & 15, ty = t >> 4;
    float acc[4][4] = {};
    for (int k0 = 0; k0 < KTOT; k0 += 16) {
#pragma unroll
        for (int m = 0; m < 4; m++)
            As[lk][lr + 16 * m] = Ah[(size_t)(i0 + lr + 16 * m) * ldA + (k0 + lk)];
        float scl = SCALEB ? rn[h * 256 + k0 + lk] : 1.f;
#pragma unroll
        for (int m = 0; m < 4; m++) {
            if (TRANSB) {
                float bv = Bh[(size_t)(j0 + lr + 16 * m) * ldB + (k0 + lk)];
                if (SCALEB) bv *= scl;
                Bs[lk][lr + 16 * m] = bv;
            } else {
                Bs[lr][lk + 16 * m] = Bh[(size_t)(k0 + lr) * ldB + (j0 + lk + 16 * m)];
            }
        }
        __syncthreads();
#pragma unroll
        for (int kk = 0; kk < 16; kk++) {
            float a4[4], b4[4];
#pragma unroll
            for (int m = 0; m < 4; m++) {
                a4[m] = As[kk][ty * 4 + m];
                b4[m] = Bs[kk][tx * 4 + m];
            }
#pragma unroll
            for (int mi = 0; mi < 4; mi++)
#pragma unroll
                for (int ni = 0; ni < 4; ni++) acc[mi][ni] += a4[mi] * b4[ni];
        }
        __syncthreads();
    }
#pragma unroll
    for (int mi = 0; mi < 4; mi++) {
        int row = i0 + ty * 4 + mi;
        float4 v4;
        v4.x = acc[mi][0]; v4.y = acc[mi][1]; v4.z = acc[mi][2]; v4.w = acc[mi][3];
        if (BIAS) {
            int col = j0 + tx * 4;
            v4.x += bias[col]; v4.y += bias[col + 1];
            v4.z += bias[col + 2]; v4.w += bias[col + 3];
        }
        *reinterpret_cast<float4*>(&Ch[(size_t)row * ldC + j0 + tx * 4]) = v4;
    }
}

// ---- P,Q,R: 32x32 tile per block, 2x2-ish micro (cols tx, tx+16) ----------
__global__ __launch_bounds__(256) void k_pqr(const float* __restrict__ w,
                                             float* __restrict__ P,
                                             float* __restrict__ Q,
                                             float* __restrict__ R) {
    int h = blockIdx.z;
    int s0 = blockIdx.x * 32, r0 = blockIdx.y * 32;
    __shared__ float aR[32][33], bR[32][33], bS[32][33], cS[32][33];
    int t = threadIdx.x;
    int ld = t & 31, lr = t >> 5;
#pragma unroll
    for (int m = 0; m < 4; m++) {
        int rr = lr + 8 * m;
        aR[rr][ld] = w[(size_t)(r0 + rr) * 512 + h * 32 + ld];
        bR[rr][ld] = w[(size_t)(r0 + rr) * 512 + 128 + h * 32 + ld];
        bS[rr][ld] = w[(size_t)(s0 + rr) * 512 + 128 + h * 32 + ld];
        cS[rr][ld] = w[(size_t)(s0 + rr) * 512 + 256 + h * 32 + ld];
    }
    __syncthreads();
    int tx = t & 15, ty = t >> 4;
    float dab[2][2] = {}, dac[2][2] = {}, dbc[2][2] = {};
#pragma unroll
    for (int dd = 0; dd < 32; dd++) {
        float av0 = aR[ty * 2][dd], av1 = aR[ty * 2 + 1][dd];
        float br0 = bR[ty * 2][dd], br1 = bR[ty * 2 + 1][dd];
        float bv0 = bS[tx][dd], bv1 = bS[tx + 16][dd];
        float cv0 = cS[tx][dd], cv1 = cS[tx + 16][dd];
        dab[0][0] += av0 * bv0; dab[0][1] += av0 * bv1;
        dab[1][0] += av1 * bv0; dab[1][1] += av1 * bv1;
        dac[0][0] += av0 * cv0; dac[0][1] += av0 * cv1;
        dac[1][0] += av1 * cv0; dac[1][1] += av1 * cv1;
        dbc[0][0] += br0 * cv0; dbc[0][1] += br0 * cv1;
        dbc[1][0] += br1 * cv0; dbc[1][1] += br1 * cv1;
    }
    const float scale = 0.17677669529663687f;
    size_t base = (size_t)h * 65536;
#pragma unroll
    for (int r = 0; r < 2; r++) {
#pragma unroll
        for (int c = 0; c < 2; c++) {
            size_t o = base + (size_t)(r0 + ty * 2 + r) * 256 + (s0 + tx + 16 * c);
            P[o] = __expf(scale * dab[r][c]);
            Q[o] = __expf(scale * dac[r][c]);
            R[o] = __expf(scale * dbc[r][c]);
        }
    }
}

// ---- rn[k] = 1 / clip(sum_i Q[i,k] T[i,k], 1e-6) --------------------------
// grid (8, H): block handles 32 k-columns; 8 i-groups x 32 k threads
__global__ __launch_bounds__(256) void k_norm(const float* __restrict__ Q,
                                              const float* __restrict__ T,
                                              float* __restrict__ rn) {
    int h = blockIdx.y;
    int k0 = blockIdx.x * 32;
    size_t hb = (size_t)h * 65536;
    int t = threadIdx.x;
    int kl = t & 31, ig = t >> 5;
    float s = 0.f;
#pragma unroll 8
    for (int ii = 0; ii < 32; ii++) {
        size_t o = hb + (size_t)(ig * 32 + ii) * 256 + k0 + kl;
        s += Q[o] * T[o];
    }
    __shared__ float red[8][32];
    red[ig][kl] = s;
    __syncthreads();
    if (ig == 0) {
        float v = red[0][kl];
#pragma unroll
        for (int m = 1; m < 8; m++) v += red[m][kl];
        v = v < 1e-6f ? 1e-6f : v;
        rn[h * 256 + k0 + kl] = 1.f / v;
    }
}

// ---- x1 = (P.*S) v, x2 = (Q.*T.*rn) v, y = x1.*x2 -------------------------
// grid (16, H): 16 rows per block; thread = (d, rl) covers rows rl, rl+8
__global__ __launch_bounds__(256) void k_x1x2(
    const float* __restrict__ P, const float* __restrict__ Q,
    const float* __restrict__ S, const float* __restrict__ T,
    const float* __restrict__ rn, const float* __restrict__ w,
    float* __restrict__ y) {
    int h = blockIdx.y;
    int i0 = blockIdx.x * 16;
    size_t hb = (size_t)h * 65536;
    __shared__ float wp[16][256];
    __shared__ float wq[16][256];
    __shared__ float vls[256][32];
    int t = threadIdx.x;
#pragma unroll
    for (int m = 0; m < 16; m++) {
        int idx = t + 256 * m;
        int rr = idx >> 8, jj = idx & 255;
        size_t o = hb + (size_t)(i0 + rr) * 256 + jj;
        wp[rr][jj] = P[o] * S[o];
        wq[rr][jj] = Q[o] * T[o] * rn[h * 256 + jj];
    }
#pragma unroll
    for (int m = 0; m < 32; m++) {
        int idx = t + 256 * m;
        int jj = idx >> 5, dd = idx & 31;
        vls[jj][dd] = w[(size_t)jj * 512 + 384 + h * 32 + dd];
    }
    __syncthreads();
    int d = t & 31, rl = t >> 5;
    float x1a = 0.f, x2a = 0.f, x1b = 0.f, x2b = 0.f;
#pragma unroll 8
    for (int j = 0; j < 256; j++) {
        float vv = vls[j][d];
        x1a += wp[rl][j] * vv;     x2a += wq[rl][j] * vv;
        x1b += wp[rl + 8][j] * vv; x2b += wq[rl + 8][j] * vv;
    }
    y[(size_t)(i0 + rl) * 128 + h * 32 + d] = x1a * x2a;
    y[(size_t)(i0 + rl + 8) * 128 + h * 32 + d] = x1b * x2b;
}

extern "C" void kernel_launch(void* const* d_in, const int* in_sizes, int n_in,
                              void* d_out, int out_size, void* d_ws, size_t ws_size,
                              hipStream_t stream) {
    const float* x      = (const float*)d_in[0];
    const float* W_w    = (const float*)d_in[1];
    const float* W_proj = (const float*)d_in[2];
    const float* b_proj = (const float*)d_in[3];
    float* out = (float*)d_out;
    float* ws  = (float*)d_ws;

    float* w  = ws + OFF_W;
    float* P  = ws + OFF_P;
    float* Q  = ws + OFF_Q;
    float* R  = ws + OFF_R;
    float* S  = ws + OFF_S;
    float* T  = ws + OFF_T;
    float* rn = ws + OFF_RN;
    float* y  = ws + OFF_Y;

    // 1. w = x @ W_w  (256x512, K=128)
    k_gemm64<128, false, false, false><<<dim3(8, 4, 1), 256, 0, stream>>>(
        x, W_w, nullptr, nullptr, w, 128, 512, 512, 0, 0, 0);
    // 2. P, Q, R
    k_pqr<<<dim3(8, 8, H), 256, 0, stream>>>(w, P, Q, R);
    // 3. T = P R  (NN, per head)
    k_gemm64<256, false, false, false><<<dim3(4, 4, H), 256, 0, stream>>>(
        P, R, nullptr, nullptr, T, 256, 256, 256, 65536, 65536, 65536);
    // 4. rn
    k_norm<<<dim3(8, H), 256, 0, stream>>>(Q, T, rn);
    // 5. S = Q (R rn)^T  (NT, B scaled at load)
    k_gemm64<256, true, true, false><<<dim3(4, 4, H), 256, 0, stream>>>(
        Q, R, rn, nullptr, S, 256, 256, 256, 65536, 65536, 65536);
    // 6. x1, x2, y
    k_x1x2<<<dim3(16, H), 256, 0, stream>>>(P, Q, S, T, rn, w, y);
    // 7. out = y @ W_proj + b_proj  (256x128, K=128)
    k_gemm64<128, false, false, true><<<dim3(2, 4, 1), 256, 0, stream>>>(
        y, W_proj, nullptr, b_proj, out, 128, 128, 128, 0, 0, 0);
}

// Round 3
// 54.669 us; speedup vs baseline: 1.4520x; 1.2230x over previous
//
#include <hip/hip_runtime.h>
#include <hip/hip_bf16.h>

// B=1, NN=256, C=128, H=4, D=32
// Factorization (O(N^3), never materialize the N^3 tensor):
//   w = x @ W_w (256x512); a,b,c,v head slices at col offsets 0,128,256,384
//   P = exp(s a b^T), Q = exp(s a c^T), R = exp(s b c^T)   (s = 1/sqrt(32))
//   T = P R ;  norm[k] = clip(sum_i Q[i,k] T[i,k], 1e-6)   (fused: atomics)
//   S[i,j] = sum_k Q[i,k] R[j,k]/norm[k]
//   x1 = (P.*S) v ; x2[i,d] = sum_k Q[i,k] T[i,k]/norm[k] v[k,d]
//   y = x1.*x2 ; out = y @ W_proj + b_proj

constexpr int H = 4;

constexpr size_t OFF_W    = 0;                  // 256*512
constexpr size_t OFF_P    = OFF_W + 131072;     // 4*65536 each
constexpr size_t OFF_Q    = OFF_P + 262144;
constexpr size_t OFF_R    = OFF_Q + 262144;
constexpr size_t OFF_S    = OFF_R + 262144;
constexpr size_t OFF_T    = OFF_S + 262144;
constexpr size_t OFF_NORM = OFF_T + 262144;     // 4*256
constexpr size_t OFF_Y    = OFF_NORM + 1024;    // 256*128

__device__ __forceinline__ float rcl(float v) {
    return 1.f / fmaxf(v, 1e-6f);
}

// ---- K1: w = x(256x128) @ Ww(128x512). 32x32 tile, 2x2 micro. Also zeros norm.
__global__ __launch_bounds__(256) void k_w(const float* __restrict__ x,
                                           const float* __restrict__ Ww,
                                           float* __restrict__ w,
                                           float* __restrict__ norm) {
    int t = threadIdx.x;
    if (blockIdx.x == 0 && blockIdx.y == 0) {
        float4 z = {0.f, 0.f, 0.f, 0.f};
        *reinterpret_cast<float4*>(&norm[t * 4]) = z;  // 256*4 = 1024
    }
    __shared__ float As[32][36];   // [i][k]
    __shared__ float BsT[32][36];  // [j][k]
    int j0 = blockIdx.x * 32, i0 = blockIdx.y * 32;
    int tx = t & 15, ty = t >> 4;
    int r = t >> 3, g = t & 7;
    float acc[2][2] = {};
    for (int k0 = 0; k0 < 128; k0 += 32) {
        float4 a4 = *reinterpret_cast<const float4*>(&x[(size_t)(i0 + r) * 128 + k0 + g * 4]);
        *reinterpret_cast<float4*>(&As[r][g * 4]) = a4;
        float4 b4 = *reinterpret_cast<const float4*>(&Ww[(size_t)(k0 + r) * 512 + j0 + g * 4]);
        BsT[g * 4 + 0][r] = b4.x;
        BsT[g * 4 + 1][r] = b4.y;
        BsT[g * 4 + 2][r] = b4.z;
        BsT[g * 4 + 3][r] = b4.w;
        __syncthreads();
#pragma unroll
        for (int kk = 0; kk < 32; kk++) {
            float a0 = As[ty * 2][kk], a1 = As[ty * 2 + 1][kk];
            float b0 = BsT[tx * 2][kk], b1 = BsT[tx * 2 + 1][kk];
            acc[0][0] += a0 * b0; acc[0][1] += a0 * b1;
            acc[1][0] += a1 * b0; acc[1][1] += a1 * b1;
        }
        __syncthreads();
    }
#pragma unroll
    for (int rr = 0; rr < 2; rr++) {
        float2 v2 = make_float2(acc[rr][0], acc[rr][1]);
        *reinterpret_cast<float2*>(&w[(size_t)(i0 + ty * 2 + rr) * 512 + j0 + tx * 2]) = v2;
    }
}

// ---- K2: P,Q,R 32x32 tiles ----
__global__ __launch_bounds__(256) void k_pqr(const float* __restrict__ w,
                                             float* __restrict__ P,
                                             float* __restrict__ Q,
                                             float* __restrict__ R) {
    int h = blockIdx.z;
    int s0 = blockIdx.x * 32, r0 = blockIdx.y * 32;
    __shared__ float aR[32][36], bR[32][36], bS[32][36], cS[32][36];
    int t = threadIdx.x;
    int rr = t >> 3, g = t & 7;
    *reinterpret_cast<float4*>(&aR[rr][g * 4]) =
        *reinterpret_cast<const float4*>(&w[(size_t)(r0 + rr) * 512 + h * 32 + g * 4]);
    *reinterpret_cast<float4*>(&bR[rr][g * 4]) =
        *reinterpret_cast<const float4*>(&w[(size_t)(r0 + rr) * 512 + 128 + h * 32 + g * 4]);
    *reinterpret_cast<float4*>(&bS[rr][g * 4]) =
        *reinterpret_cast<const float4*>(&w[(size_t)(s0 + rr) * 512 + 128 + h * 32 + g * 4]);
    *reinterpret_cast<float4*>(&cS[rr][g * 4]) =
        *reinterpret_cast<const float4*>(&w[(size_t)(s0 + rr) * 512 + 256 + h * 32 + g * 4]);
    __syncthreads();
    int tx = t & 15, ty = t >> 4;
    float dab[2][2] = {}, dac[2][2] = {}, dbc[2][2] = {};
#pragma unroll
    for (int d = 0; d < 32; d++) {
        float a0 = aR[ty * 2][d], a1 = aR[ty * 2 + 1][d];
        float p0 = bR[ty * 2][d], p1 = bR[ty * 2 + 1][d];
        float b0 = bS[tx * 2][d], b1 = bS[tx * 2 + 1][d];
        float c0 = cS[tx * 2][d], c1 = cS[tx * 2 + 1][d];
        dab[0][0] += a0 * b0; dab[0][1] += a0 * b1;
        dab[1][0] += a1 * b0; dab[1][1] += a1 * b1;
        dac[0][0] += a0 * c0; dac[0][1] += a0 * c1;
        dac[1][0] += a1 * c0; dac[1][1] += a1 * c1;
        dbc[0][0] += p0 * c0; dbc[0][1] += p0 * c1;
        dbc[1][0] += p1 * c0; dbc[1][1] += p1 * c1;
    }
    const float scale = 0.17677669529663687f;
    size_t hb = (size_t)h * 65536;
#pragma unroll
    for (int rr2 = 0; rr2 < 2; rr2++) {
        size_t o = hb + (size_t)(r0 + ty * 2 + rr2) * 256 + s0 + tx * 2;
        *reinterpret_cast<float2*>(&P[o]) =
            make_float2(__expf(scale * dab[rr2][0]), __expf(scale * dab[rr2][1]));
        *reinterpret_cast<float2*>(&Q[o]) =
            make_float2(__expf(scale * dac[rr2][0]), __expf(scale * dac[rr2][1]));
        *reinterpret_cast<float2*>(&R[o]) =
            make_float2(__expf(scale * dbc[rr2][0]), __expf(scale * dbc[rr2][1]));
    }
}

// ---- K3: T = P R (NN) + fused norm atomics. 32x32 tile per block. ----
__global__ __launch_bounds__(256) void k_T(const float* __restrict__ P,
                                           const float* __restrict__ R,
                                           const float* __restrict__ Q,
                                           float* __restrict__ T,
                                           float* __restrict__ norm) {
    int h = blockIdx.z;
    size_t hb = (size_t)h * 65536;
    int k0 = blockIdx.x * 32, i0 = blockIdx.y * 32;
    __shared__ float As[32][36];   // P[i][j]
    __shared__ float BsT[32][36];  // R^T: [k][j]
    __shared__ float red[16][34];
    int t = threadIdx.x;
    int tx = t & 15, ty = t >> 4;
    int r = t >> 3, g = t & 7;
    float acc[2][2] = {};
    for (int j0 = 0; j0 < 256; j0 += 32) {
        float4 a4 = *reinterpret_cast<const float4*>(&P[hb + (size_t)(i0 + r) * 256 + j0 + g * 4]);
        *reinterpret_cast<float4*>(&As[r][g * 4]) = a4;
        float4 b4 = *reinterpret_cast<const float4*>(&R[hb + (size_t)(j0 + r) * 256 + k0 + g * 4]);
        BsT[g * 4 + 0][r] = b4.x;
        BsT[g * 4 + 1][r] = b4.y;
        BsT[g * 4 + 2][r] = b4.z;
        BsT[g * 4 + 3][r] = b4.w;
        __syncthreads();
#pragma unroll
        for (int kk = 0; kk < 32; kk++) {
            float a0 = As[ty * 2][kk], a1 = As[ty * 2 + 1][kk];
            float b0 = BsT[tx * 2][kk], b1 = BsT[tx * 2 + 1][kk];
            acc[0][0] += a0 * b0; acc[0][1] += a0 * b1;
            acc[1][0] += a1 * b0; acc[1][1] += a1 * b1;
        }
        __syncthreads();
    }
    int i = i0 + ty * 2, k = k0 + tx * 2;
    *reinterpret_cast<float2*>(&T[hb + (size_t)i * 256 + k]) = make_float2(acc[0][0], acc[0][1]);
    *reinterpret_cast<float2*>(&T[hb + (size_t)(i + 1) * 256 + k]) = make_float2(acc[1][0], acc[1][1]);
    // norm partial: sum_i Q[i,k]*T[i,k] over this tile's rows
    float2 q0 = *reinterpret_cast<const float2*>(&Q[hb + (size_t)i * 256 + k]);
    float2 q1 = *reinterpret_cast<const float2*>(&Q[hb + (size_t)(i + 1) * 256 + k]);
    red[ty][tx * 2]     = q0.x * acc[0][0] + q1.x * acc[1][0];
    red[ty][tx * 2 + 1] = q0.y * acc[0][1] + q1.y * acc[1][1];
    __syncthreads();
    if (t < 32) {
        float s = 0.f;
#pragma unroll
        for (int m = 0; m < 16; m++) s += red[m][t];
        atomicAdd(&norm[h * 256 + k0 + t], s);
    }
}

// ---- K4: S = Q (R/norm)^T (NT). 32x32 tile. ----
__global__ __launch_bounds__(256) void k_S(const float* __restrict__ Q,
                                           const float* __restrict__ R,
                                           const float* __restrict__ norm,
                                           float* __restrict__ S) {
    int h = blockIdx.z;
    size_t hb = (size_t)h * 65536;
    int j0 = blockIdx.x * 32, i0 = blockIdx.y * 32;
    __shared__ float As[32][36];  // Q[i][k]
    __shared__ float Bs[32][36];  // (R*rn)[j][k]
    int t = threadIdx.x;
    int tx = t & 15, ty = t >> 4;
    int r = t >> 3, g = t & 7;
    float acc[2][2] = {};
    for (int k0 = 0; k0 < 256; k0 += 32) {
        float4 a4 = *reinterpret_cast<const float4*>(&Q[hb + (size_t)(i0 + r) * 256 + k0 + g * 4]);
        *reinterpret_cast<float4*>(&As[r][g * 4]) = a4;
        float4 b4 = *reinterpret_cast<const float4*>(&R[hb + (size_t)(j0 + r) * 256 + k0 + g * 4]);
        float4 n4 = *reinterpret_cast<const float4*>(&norm[h * 256 + k0 + g * 4]);
        b4.x *= rcl(n4.x); b4.y *= rcl(n4.y); b4.z *= rcl(n4.z); b4.w *= rcl(n4.w);
        *reinterpret_cast<float4*>(&Bs[r][g * 4]) = b4;
        __syncthreads();
#pragma unroll
        for (int kk = 0; kk < 32; kk++) {
            float a0 = As[ty * 2][kk], a1 = As[ty * 2 + 1][kk];
            float b0 = Bs[tx * 2][kk], b1 = Bs[tx * 2 + 1][kk];
            acc[0][0] += a0 * b0; acc[0][1] += a0 * b1;
            acc[1][0] += a1 * b0; acc[1][1] += a1 * b1;
        }
        __syncthreads();
    }
#pragma unroll
    for (int rr = 0; rr < 2; rr++) {
        *reinterpret_cast<float2*>(&S[hb + (size_t)(i0 + ty * 2 + rr) * 256 + j0 + tx * 2]) =
            make_float2(acc[rr][0], acc[rr][1]);
    }
}

// ---- K5: x1=(P.*S)v, x2=(Q.*T.*rn)v, y=x1.*x2. 8 rows/block, grid (32,H). ----
__global__ __launch_bounds__(256) void k_x1x2(
    const float* __restrict__ P, const float* __restrict__ Q,
    const float* __restrict__ S, const float* __restrict__ T,
    const float* __restrict__ norm, const float* __restrict__ w,
    float* __restrict__ y) {
    int h = blockIdx.y;
    int i0 = blockIdx.x * 8;
    size_t hb = (size_t)h * 65536;
    __shared__ float wp[8][256];
    __shared__ float wq[8][256];
    __shared__ float vls[256][32];
    int t = threadIdx.x;
#pragma unroll
    for (int m = 0; m < 2; m++) {
        int lin = (m * 256 + t) * 4;
        int rr = lin >> 8, jj = lin & 255;
        size_t o = hb + (size_t)(i0 + rr) * 256 + jj;
        float4 p4 = *reinterpret_cast<const float4*>(&P[o]);
        float4 s4 = *reinterpret_cast<const float4*>(&S[o]);
        float4 q4 = *reinterpret_cast<const float4*>(&Q[o]);
        float4 t4 = *reinterpret_cast<const float4*>(&T[o]);
        float4 n4 = *reinterpret_cast<const float4*>(&norm[h * 256 + jj]);
        float4 wpv, wqv;
        wpv.x = p4.x * s4.x; wpv.y = p4.y * s4.y; wpv.z = p4.z * s4.z; wpv.w = p4.w * s4.w;
        wqv.x = q4.x * t4.x * rcl(n4.x); wqv.y = q4.y * t4.y * rcl(n4.y);
        wqv.z = q4.z * t4.z * rcl(n4.z); wqv.w = q4.w * t4.w * rcl(n4.w);
        *reinterpret_cast<float4*>(&wp[rr][jj]) = wpv;
        *reinterpret_cast<float4*>(&wq[rr][jj]) = wqv;
    }
#pragma unroll
    for (int m = 0; m < 8; m++) {
        int lin = (m * 256 + t) * 4;
        int jj = lin >> 5, dd = lin & 31;
        *reinterpret_cast<float4*>(&vls[jj][dd]) =
            *reinterpret_cast<const float4*>(&w[(size_t)jj * 512 + 384 + h * 32 + dd]);
    }
    __syncthreads();
    int d = t & 31, rl = t >> 5;
    float x1 = 0.f, x2 = 0.f;
#pragma unroll 8
    for (int j = 0; j < 256; j++) {
        float vv = vls[j][d];
        x1 += wp[rl][j] * vv;
        x2 += wq[rl][j] * vv;
    }
    y[(size_t)(i0 + rl) * 128 + h * 32 + d] = x1 * x2;
}

// ---- K6: out = y @ W_proj + b_proj. 32x32 tile. ----
__global__ __launch_bounds__(256) void k_proj(const float* __restrict__ y,
                                              const float* __restrict__ Wp,
                                              const float* __restrict__ bp,
                                              float* __restrict__ out) {
    __shared__ float As[32][36];
    __shared__ float BsT[32][36];
    int j0 = blockIdx.x * 32, i0 = blockIdx.y * 32;
    int t = threadIdx.x;
    int tx = t & 15, ty = t >> 4;
    int r = t >> 3, g = t & 7;
    float acc[2][2] = {};
    for (int k0 = 0; k0 < 128; k0 += 32) {
        float4 a4 = *reinterpret_cast<const float4*>(&y[(size_t)(i0 + r) * 128 + k0 + g * 4]);
        *reinterpret_cast<float4*>(&As[r][g * 4]) = a4;
        float4 b4 = *reinterpret_cast<const float4*>(&Wp[(size_t)(k0 + r) * 128 + j0 + g * 4]);
        BsT[g * 4 + 0][r] = b4.x;
        BsT[g * 4 + 1][r] = b4.y;
        BsT[g * 4 + 2][r] = b4.z;
        BsT[g * 4 + 3][r] = b4.w;
        __syncthreads();
#pragma unroll
        for (int kk = 0; kk < 32; kk++) {
            float a0 = As[ty * 2][kk], a1 = As[ty * 2 + 1][kk];
            float b0 = BsT[tx * 2][kk], b1 = BsT[tx * 2 + 1][kk];
            acc[0][0] += a0 * b0; acc[0][1] += a0 * b1;
            acc[1][0] += a1 * b0; acc[1][1] += a1 * b1;
        }
        __syncthreads();
    }
    float bb0 = bp[j0 + tx * 2], bb1 = bp[j0 + tx * 2 + 1];
#pragma unroll
    for (int rr = 0; rr < 2; rr++) {
        *reinterpret_cast<float2*>(&out[(size_t)(i0 + ty * 2 + rr) * 128 + j0 + tx * 2]) =
            make_float2(acc[rr][0] + bb0, acc[rr][1] + bb1);
    }
}

extern "C" void kernel_launch(void* const* d_in, const int* in_sizes, int n_in,
                              void* d_out, int out_size, void* d_ws, size_t ws_size,
                              hipStream_t stream) {
    const float* x      = (const float*)d_in[0];
    const float* W_w    = (const float*)d_in[1];
    const float* W_proj = (const float*)d_in[2];
    const float* b_proj = (const float*)d_in[3];
    float* out = (float*)d_out;
    float* ws  = (float*)d_ws;

    float* w    = ws + OFF_W;
    float* P    = ws + OFF_P;
    float* Q    = ws + OFF_Q;
    float* R    = ws + OFF_R;
    float* S    = ws + OFF_S;
    float* T    = ws + OFF_T;
    float* norm = ws + OFF_NORM;
    float* y    = ws + OFF_Y;

    k_w<<<dim3(16, 8), 256, 0, stream>>>(x, W_w, w, norm);
    k_pqr<<<dim3(8, 8, H), 256, 0, stream>>>(w, P, Q, R);
    k_T<<<dim3(8, 8, H), 256, 0, stream>>>(P, R, Q, T, norm);
    k_S<<<dim3(8, 8, H), 256, 0, stream>>>(Q, R, norm, S);
    k_x1x2<<<dim3(32, H), 256, 0, stream>>>(P, Q, S, T, norm, w, y);
    k_proj<<<dim3(4, 8), 256, 0, stream>>>(y, W_proj, b_proj, out);
}